// Round 7
// baseline (363.151 us; speedup 1.0000x reference)
//
#include <hip/hip_runtime.h>

#define B_ 512
#define L_ 512
#define N_ 128
#define TM 256          // boundary: fwd produces alpha_255, bwd produces beta_255
#define C_BIAS 3.0f

typedef _Float16 h2_t __attribute__((ext_vector_type(2)));
typedef unsigned int u32v __attribute__((ext_vector_type(32)));  // 32 packed h2 = 64 f16

__device__ __forceinline__ float dot2f(h2_t a, h2_t b, float c) {
#if __has_builtin(__builtin_amdgcn_fdot2)
    return __builtin_amdgcn_fdot2(a, b, c, false);
#else
    return c + (float)a[0] * (float)b[0] + (float)a[1] * (float)b[1];
#endif
}

__device__ __forceinline__ unsigned packh2(float x, float y) {
    h2_t h; h[0] = (_Float16)x; h[1] = (_Float16)y;
    return __builtin_bit_cast(unsigned, h);
}
__device__ __forceinline__ h2_t u2h2(unsigned u) {
    return __builtin_bit_cast(h2_t, u);
}

// ---- full-rate VALU wave-64 reductions via DPP ----
#define DPP_STEP_MAX(v, ctrl)                                                   \
    {                                                                           \
        int _t = __builtin_amdgcn_update_dpp(__float_as_int(v),                 \
                    __float_as_int(v), ctrl, 0xf, 0xf, false);                  \
        v = fmaxf(v, __int_as_float(_t));                                       \
    }
#define DPP_STEP_ADD(v, ctrl)                                                   \
    {                                                                           \
        int _t = __builtin_amdgcn_update_dpp(__float_as_int(v),                 \
                    __float_as_int(v), ctrl, 0xf, 0xf, false);                  \
        v = v + __int_as_float(_t);                                             \
    }

__device__ __forceinline__ float wave_max(float v) {
    DPP_STEP_MAX(v, 0xB1);   // quad_perm [1,0,3,2]
    DPP_STEP_MAX(v, 0x4E);   // quad_perm [2,3,0,1]
    DPP_STEP_MAX(v, 0x141);  // row_half_mirror
    DPP_STEP_MAX(v, 0x140);  // row_mirror
    DPP_STEP_MAX(v, 0x142);  // row_bcast15
    DPP_STEP_MAX(v, 0x143);  // row_bcast31
    return __int_as_float(__builtin_amdgcn_readlane(__float_as_int(v), 63));
}
__device__ __forceinline__ float wave_sum(float v) {
    DPP_STEP_ADD(v, 0xB1);
    DPP_STEP_ADD(v, 0x4E);
    DPP_STEP_ADD(v, 0x141);
    DPP_STEP_ADD(v, 0x140);
    DPP_STEP_ADD(v, 0x142);
    DPP_STEP_ADD(v, 0x143);
    return __int_as_float(__builtin_amdgcn_readlane(__float_as_int(v), 63));
}

// LDS-only barrier: waits lgkmcnt(0) but does NOT drain vmcnt -> global
// prefetch loads stay in flight across the barrier.
__device__ __forceinline__ void lds_barrier() {
    asm volatile("s_waitcnt lgkmcnt(0)\n\ts_barrier" ::: "memory");
}

// s = sum over 128 states: E[pair p] . ET[pair p]; ET held as SSA vectors.
__device__ __forceinline__ float dot128(const h2_t* Erd, u32v ua, u32v ub) {
    const float4* E4 = (const float4*)Erd;
    float a0 = 0.f, a1 = 0.f, a2 = 0.f, a3 = 0.f;
    float a4 = 0.f, a5 = 0.f, a6 = 0.f, a7 = 0.f;
#pragma unroll
    for (int r = 0; r < 8; ++r) {
        float4 blk = E4[r];
        const h2_t* e2 = (const h2_t*)&blk;
        a0 = dot2f(e2[0], u2h2(ua[4 * r + 0]), a0);
        a1 = dot2f(e2[1], u2h2(ua[4 * r + 1]), a1);
        a2 = dot2f(e2[2], u2h2(ua[4 * r + 2]), a2);
        a3 = dot2f(e2[3], u2h2(ua[4 * r + 3]), a3);
    }
#pragma unroll
    for (int r = 0; r < 8; ++r) {
        float4 blk = E4[8 + r];
        const h2_t* e2 = (const h2_t*)&blk;
        a4 = dot2f(e2[0], u2h2(ub[4 * r + 0]), a4);
        a5 = dot2f(e2[1], u2h2(ub[4 * r + 1]), a5);
        a6 = dot2f(e2[2], u2h2(ub[4 * r + 2]), a6);
        a7 = dot2f(e2[3], u2h2(ub[4 * r + 3]), a7);
    }
    return ((a0 + a1) + (a2 + a3)) + ((a4 + a5) + (a6 + a7));
}

// ---------------------------------------------------------------------------
// norm_kernel: 1024 blocks x 128 threads (2 waves) = 2 waves/SIMD.
// b = blockIdx>>1 ; bw = blockIdx&1 (0 = fwd t=0..255, 1 = bwd t=511..255).
// Lane owns ONE state (tid). ET fragment lives in two u32v SSA vectors
// (64 arch VGPRs — no alloca, no AGPR demotion). E/F vector + per-step max
// exchanged through parity double-buffered LDS; one LDS-only barrier/step.
// Lag-1 max normalization (validated absmax 0.0 in rounds 4-6).
// ---------------------------------------------------------------------------
__global__ __launch_bounds__(128, 2) void norm_kernel(
    const float* __restrict__ em, const int* __restrict__ tg,
    const float* __restrict__ mask, const float* __restrict__ st,
    const float* __restrict__ trans,
    float* __restrict__ alpha, float* __restrict__ beta,
    float* __restrict__ pathf, float* __restrict__ pathb)
{
    __shared__ __align__(16) h2_t Ehb[2][64];   // E/F vector, parity buffered
    __shared__ __align__(8)  float pm2[2][2];   // per-wave max, parity buffered
    __shared__ float Mlds[TM];                  // mask half-row
    __shared__ float pred[2];

    const int tid = threadIdx.x;     // == state index
    const int w   = tid >> 6;
    const int l   = tid & 63;
    const int b   = blockIdx.x >> 1;
    const int bw  = blockIdx.x & 1;
    const size_t base = (size_t)b * L_ * N_;
    const int bL = b * L_;

    if (bw == 0) {
        // ================= FORWARD =================
        float pacc = 0.f;
        for (int t = 1 + tid; t < TM; t += 128) {
            int cur  = tg[bL + t];
            int prev = tg[bL + t - 1];
            pacc += mask[bL + t] * (trans[prev * N_ + cur] + em[base + (size_t)t * N_ + cur]);
        }
        pacc = wave_sum(pacc);
        if (l == 0) pred[w] = pacc;

        Mlds[tid]       = mask[bL + tid];
        Mlds[tid + 128] = mask[bL + tid + 128];

        // ET column fragment (states i paired): ua pair k = (i=2k, 2k+1), ub: i+64
        u32v ua, ub;
#pragma unroll
        for (int k = 0; k < 32; ++k) {
            ua[k] = packh2(__expf(trans[(2 * k     ) * N_ + tid]),
                           __expf(trans[(2 * k +  1) * N_ + tid]));
            ub[k] = packh2(__expf(trans[(2 * k + 64) * N_ + tid]),
                           __expf(trans[(2 * k + 65) * N_ + tid]));
        }

        // init: ns_0, exact max, E_0 -> buffer 0
        float ns = st[tid] + em[base + tid];
        {
            float mxw = wave_max(ns);
            if (l == 0) pm2[0][w] = mxw;
        }
        __syncthreads();
        if (tid == 0) {
            int t0 = tg[bL];
            pathf[b] = pred[0] + pred[1] + st[t0] + em[base + t0];
        }
        float2 pmv0 = *(const float2*)pm2[0];
        float Mstar = fmaxf(pmv0.x, pmv0.y);
        ((_Float16*)Ehb[0])[tid] = (_Float16)__expf(ns - Mstar - C_BIAS);
        float Mcarry = Mstar;

        float pipe0 = em[base + (size_t)1 * N_ + tid];
        float pipe1 = em[base + (size_t)2 * N_ + tid];
        float pipe2 = em[base + (size_t)3 * N_ + tid];
        float pipe3 = em[base + (size_t)4 * N_ + tid];

#define FWD_STEP(T, SLOT, RD, WR)                                               \
        {                                                                       \
            lds_barrier();                                                      \
            float emv = SLOT;                                                   \
            int tpf = (T) + 4; if (tpf > TM - 1) tpf = TM - 1;                  \
            SLOT = em[base + (size_t)tpf * N_ + tid];                           \
            float2 pmv = *(const float2*)pm2[RD];                               \
            float Ms = fmaxf(pmv.x, pmv.y);                                     \
            float mk = Mlds[T];                                                 \
            float s = dot128(Ehb[RD], ua, ub);                                  \
            float nxt = __logf(s) + Mcarry + C_BIAS + emv;                      \
            ns = mk * nxt + (1.f - mk) * ns;                                    \
            float mxw = wave_max(ns);                                           \
            if (l == 0) pm2[WR][w] = mxw;                                       \
            ((_Float16*)Ehb[WR])[tid] = (_Float16)__expf(ns - Ms - C_BIAS);     \
            Mcarry = Ms;                                                        \
        }

        for (int tt = 1; tt + 3 < TM; tt += 4) {
            FWD_STEP(tt    , pipe0, 0, 1);
            FWD_STEP(tt + 1, pipe1, 1, 0);
            FWD_STEP(tt + 2, pipe2, 0, 1);
            FWD_STEP(tt + 3, pipe3, 1, 0);
        }
        FWD_STEP(TM - 3, pipe0, 0, 1);
        FWD_STEP(TM - 2, pipe1, 1, 0);
        FWD_STEP(TM - 1, pipe2, 0, 1);
#undef FWD_STEP

        alpha[b * N_ + tid] = ns;
    } else {
        // ================= BACKWARD =================
        float pacc = 0.f;
        for (int t = TM + tid; t < L_; t += 128) {
            int cur  = tg[bL + t];
            int prev = tg[bL + t - 1];
            pacc += mask[bL + t] * (trans[prev * N_ + cur] + em[base + (size_t)t * N_ + cur]);
        }
        pacc = wave_sum(pacc);
        if (l == 0) pred[w] = pacc;

        Mlds[tid]       = mask[bL + TM + tid];
        Mlds[tid + 128] = mask[bL + TM + tid + 128];

        // ET row fragment (states j paired): ua pair k = (j=2k, 2k+1), ub: j+64
        u32v ua, ub;
#pragma unroll
        for (int k = 0; k < 32; ++k) {
            float2 q0 = *(const float2*)(trans + tid * N_ + 2 * k);
            float2 q1 = *(const float2*)(trans + tid * N_ + 2 * k + 64);
            ua[k] = packh2(__expf(q0.x), __expf(q0.y));
            ub[k] = packh2(__expf(q1.x), __expf(q1.y));
        }

        // init at t=511: beta=0, v = em_511
        float bsc = 0.f;
        float v = em[base + (size_t)(L_ - 1) * N_ + tid];
        {
            float mxw = wave_max(v);
            if (l == 0) pm2[0][w] = mxw;
        }
        __syncthreads();
        if (tid == 0) pathb[b] = pred[0] + pred[1];
        float2 pmv0 = *(const float2*)pm2[0];
        float Mstar = fmaxf(pmv0.x, pmv0.y);
        ((_Float16*)Ehb[0])[tid] = (_Float16)__expf(v - Mstar - C_BIAS);
        float Mcarry = Mstar;

        float pipe0 = em[base + (size_t)510 * N_ + tid];
        float pipe1 = em[base + (size_t)509 * N_ + tid];
        float pipe2 = em[base + (size_t)508 * N_ + tid];
        float pipe3 = em[base + (size_t)507 * N_ + tid];

#define BWD_STEP(T, SLOT, RD, WR)                                               \
        {                                                                       \
            lds_barrier();                                                      \
            float emv = SLOT;                                                   \
            int tpf = (T) - 4; if (tpf < TM - 1) tpf = TM - 1;                  \
            SLOT = em[base + (size_t)tpf * N_ + tid];                           \
            float2 pmv = *(const float2*)pm2[RD];                               \
            float Ms = fmaxf(pmv.x, pmv.y);                                     \
            float mk = Mlds[(T) + 1 - TM];                                      \
            float s = dot128(Ehb[RD], ua, ub);                                  \
            float upd = __logf(s) + Mcarry + C_BIAS;                            \
            bsc = mk * upd + (1.f - mk) * bsc;                                  \
            v = bsc + emv;                                                      \
            float mxw = wave_max(v);                                            \
            if (l == 0) pm2[WR][w] = mxw;                                       \
            ((_Float16*)Ehb[WR])[tid] = (_Float16)__expf(v - Ms - C_BIAS);      \
            Mcarry = Ms;                                                        \
        }

        for (int tt = 510; tt >= 258; tt -= 4) {   // t = 510..255, 256 steps
            BWD_STEP(tt    , pipe0, 0, 1);
            BWD_STEP(tt - 1, pipe1, 1, 0);
            BWD_STEP(tt - 2, pipe2, 0, 1);
            BWD_STEP(tt - 3, pipe3, 1, 0);
        }
#undef BWD_STEP

        beta[b * N_ + tid] = bsc;
    }
}

// ---------------------------------------------------------------------------
__global__ __launch_bounds__(1024) void combine_kernel(
    const float* __restrict__ alpha, const float* __restrict__ beta,
    const float* __restrict__ pathf, const float* __restrict__ pathb,
    float* __restrict__ out)
{
    __shared__ float part[16];
    const int tid = threadIdx.x;
    const int w = tid >> 6;
    const int l = tid & 63;
    float acc = 0.f;
    for (int k = 0; k < 32; ++k) {
        int b = w * 32 + k;
        float2 av = *(const float2*)(alpha + b * N_ + 2 * l);
        float2 bv = *(const float2*)(beta  + b * N_ + 2 * l);
        float v0 = av.x + bv.x;
        float v1 = av.y + bv.y;
        float m = wave_max(fmaxf(v0, v1));
        float s = wave_sum(__expf(v0 - m) + __expf(v1 - m));
        if (l == 0) acc += m + __logf(s) - pathf[b] - pathb[b];
    }
    if (l == 0) part[w] = acc;
    __syncthreads();
    if (tid == 0) {
        float t = 0.f;
#pragma unroll
        for (int i = 0; i < 16; ++i) t += part[i];
        out[0] = t / (float)B_;
    }
}

// ---------------------------------------------------------------------------
extern "C" void kernel_launch(void* const* d_in, const int* in_sizes, int n_in,
                              void* d_out, int out_size, void* d_ws, size_t ws_size,
                              hipStream_t stream) {
    const float* emission    = (const float*)d_in[0];
    const int*   target      = (const int*)  d_in[1];
    const float* mask        = (const float*)d_in[2];
    const float* start_trans = (const float*)d_in[3];
    const float* trans       = (const float*)d_in[4];
    float* out = (float*)d_out;

    float* ws_f  = (float*)d_ws;
    float* alpha = ws_f;                    // 512*128
    float* beta  = ws_f + B_ * N_;          // 512*128
    float* pathf = ws_f + 2 * B_ * N_;      // 512
    float* pathb = ws_f + 2 * B_ * N_ + B_; // 512

    norm_kernel   <<<2 * B_, 128, 0, stream>>>(emission, target, mask, start_trans,
                                               trans, alpha, beta, pathf, pathb);
    combine_kernel<<<1, 1024, 0, stream>>>(alpha, beta, pathf, pathb, out);
}